// Round 6
// baseline (488.045 us; speedup 1.0000x reference)
//
#include <hip/hip_runtime.h>
#include <hip/hip_fp16.h>

#define N_NODES 100000
#define N_EDGES 1600000
#define IN_SIZE 256
#define HID 64
#define HEADS 2
#define DMODEL 128   // HEADS*HID
#define OUT_SZ 16

// CSR build via bucketed counting sort (r2 geometry — measured best)
#define BSHIFT 9                       // 512 nodes per bucket
#define BNODES 512
#define NB 196                         // ceil(100000/512)
#define CAP 16384                      // bucket capacity (mean 8163, +90 sigma)
#define EPB 4096                       // edges per bin_kernel block

typedef _Float16 f16x4 __attribute__((ext_vector_type(4)));
typedef _Float16 f16x8 __attribute__((ext_vector_type(8)));
typedef float f32x4 __attribute__((ext_vector_type(4)));

// ---------------------------------------------------------------------------
// Phase 1: bin edges by dst>>9 into per-bucket regions.
// ---------------------------------------------------------------------------

__global__ __launch_bounds__(256) void bin_kernel(const int* __restrict__ src,
                                                  const int* __restrict__ dst,
                                                  int* __restrict__ counts,
                                                  int2* __restrict__ bucketbuf, int e) {
    __shared__ int hist[NB];
    __shared__ int base[NB];
    int tid = threadIdx.x;
    int start = blockIdx.x * EPB;
    for (int i = tid; i < NB; i += 256) hist[i] = 0;
    __syncthreads();
    int pack[16];
    #pragma unroll
    for (int i = 0; i < 16; i++) {
        int idx = start + i * 256 + tid;
        int p = -1;
        if (idx < e) {
            int b = dst[idx] >> BSHIFT;
            int r = atomicAdd(&hist[b], 1);     // LDS atomic: local rank
            p = (b << 16) | r;
        }
        pack[i] = p;
    }
    __syncthreads();
    for (int i = tid; i < NB; i += 256)
        base[i] = atomicAdd(&counts[i], hist[i]);   // reserve chunk per bucket
    __syncthreads();
    #pragma unroll
    for (int i = 0; i < 16; i++) {
        int idx = start + i * 256 + tid;
        int p = pack[i];
        if (p >= 0) {
            int b = p >> 16;
            int pos = base[b] + (p & 0xffff);
            if (pos < CAP)
                bucketbuf[(size_t)b * CAP + pos] = make_int2(src[idx], dst[idx]);
        }
    }
}

__global__ void bucket_scan_kernel(const int* __restrict__ counts,
                                   int* __restrict__ bases) {
    __shared__ int lds[256];
    int tid = threadIdx.x;
    int t = (tid < NB) ? min(counts[tid], CAP) : 0;
    lds[tid] = t;
    __syncthreads();
    for (int off = 1; off < 256; off <<= 1) {
        int x = 0;
        if (tid >= off) x = lds[tid - off];
        __syncthreads();
        lds[tid] += x;
        __syncthreads();
    }
    if (tid < NB) bases[tid] = lds[tid] - t;
}

// ---------------------------------------------------------------------------
// Phase 2: per-bucket CSR (all-LDS histogram/scan/scatter; L2-local writes).
// Writes src-only edge list in CSR order (ssrc) — dst is implicit (= node).
// ---------------------------------------------------------------------------

__global__ __launch_bounds__(256) void csr_kernel(const int2* __restrict__ bucketbuf,
                                                  const int* __restrict__ counts,
                                                  const int* __restrict__ bases,
                                                  int* __restrict__ deg,
                                                  int* __restrict__ offs,
                                                  int* __restrict__ ssrc, int n) {
    __shared__ int hist[BNODES];
    __shared__ int cursor[BNODES];
    __shared__ int lds[256];
    int b = blockIdx.x;
    int tid = threadIdx.x;
    int cnt = min(counts[b], CAP);
    int base = bases[b];
    int node0 = b << BSHIFT;
    const int2* ebuf = bucketbuf + (size_t)b * CAP;

    hist[tid] = 0;
    hist[tid + 256] = 0;
    __syncthreads();
    for (int i = tid; i < cnt; i += 256)
        atomicAdd(&hist[ebuf[i].y - node0], 1);
    __syncthreads();

    int h0 = hist[2 * tid], h1 = hist[2 * tid + 1];
    lds[tid] = h0 + h1;
    __syncthreads();
    for (int off = 1; off < 256; off <<= 1) {
        int x = 0;
        if (tid >= off) x = lds[tid - off];
        __syncthreads();
        lds[tid] += x;
        __syncthreads();
    }
    int excl = lds[tid] - (h0 + h1);
    cursor[2 * tid] = excl;
    cursor[2 * tid + 1] = excl + h0;
    int g0 = node0 + 2 * tid, g1 = g0 + 1;
    if (g0 < n) { deg[g0] = h0; offs[g0] = base + excl; }
    if (g1 < n) { deg[g1] = h1; offs[g1] = base + excl + h0; }
    __syncthreads();

    for (int i = tid; i < cnt; i += 256) {
        int2 ed = ebuf[i];
        int p = atomicAdd(&cursor[ed.y - node0], 1);   // LDS atomic
        ssrc[base + p] = ed.x;                         // src in CSR order
    }
}

// ---------------------------------------------------------------------------
// W transpose + fp16 cast: W[K][128] fp32 -> Wt[128][K] fp16.  Tiny (<=128KB).
// ---------------------------------------------------------------------------

template <int K>
__global__ void wt_kernel(const float* __restrict__ W, _Float16* __restrict__ Wt) {
    int i = blockIdx.x * blockDim.x + threadIdx.x;
    if (i >= 128 * K) return;
    int nr = i / K;
    int k = i - nr * K;
    Wt[i] = (_Float16)W[(size_t)k * 128 + nr];
}

// ---------------------------------------------------------------------------
// Fused MFMA GEMM + attention coefficients + fp16 pack.
//   h = A[n][K] @ W[K][128]  (fp16 inputs, fp32 accum)
//   el[n][h], er[n][h] computed in-register from the accumulators
//   h16[n][128] = fp16(h)   (compact; the ONLY materialization of h)
// F16IN=false: A is fp32 [n][K]; F16IN=true: A is packed fp16 (uint32 pairs,
// h16 layout, K/2 u32 per row; u32 j <-> cols (2j, 2j+1)).
// ---------------------------------------------------------------------------

template <int K, bool F16IN>
__global__ __launch_bounds__(256) void gemm_attn_kernel(const void* __restrict__ Ap,
                                                        const _Float16* __restrict__ Wt,
                                                        const float* __restrict__ al,
                                                        const float* __restrict__ ar,
                                                        uint32_t* __restrict__ h16,
                                                        float* __restrict__ el,
                                                        float* __restrict__ er, int n) {
    __shared__ _Float16 As[64 * 72];
    __shared__ _Float16 Bs[128 * 72];
    int tid = threadIdx.x;
    int w = tid >> 6;
    int lane = tid & 63;
    int c = lane & 15;
    int quad = lane >> 4;
    int r0 = blockIdx.x * 64;

    f32x4 acc[8];
    #pragma unroll
    for (int t = 0; t < 8; t++) acc[t] = (f32x4){0.f, 0.f, 0.f, 0.f};

    for (int kt = 0; kt < K; kt += 64) {
        // stage A tile (64 rows x 64 k)
        {
            int lr = tid >> 4;           // 0..15
            int lc = (tid & 15) * 4;     // 0..60 (halves)
            #pragma unroll
            for (int q = 0; q < 4; q++) {
                int row = lr + 16 * q;
                int gr = r0 + row;
                if constexpr (F16IN) {
                    const uint32_t* Af = (const uint32_t*)Ap;
                    uint2 v = make_uint2(0u, 0u);
                    if (gr < n) v = *(const uint2*)(Af + (size_t)gr * (K / 2) + (kt + lc) / 2);
                    *(uint2*)(As + row * 72 + lc) = v;
                } else {
                    const float* Af = (const float*)Ap;
                    float4 v = make_float4(0.f, 0.f, 0.f, 0.f);
                    if (gr < n) v = *(const float4*)(Af + (size_t)gr * K + kt + lc);
                    f16x4 hv = {(_Float16)v.x, (_Float16)v.y, (_Float16)v.z, (_Float16)v.w};
                    *(f16x4*)(As + row * 72 + lc) = hv;
                }
            }
            // stage Wt tile (128 n-rows x 64 k), fp16; 32 halves per thread
            int nr = tid >> 1;           // 0..127
            int kc = (tid & 1) * 32;     // 0 or 32
            const uint4* gsrc = (const uint4*)(Wt + (size_t)nr * K + kt + kc);
            uint4 v0 = gsrc[0];
            uint4 v1 = gsrc[1];
            uint4 v2 = gsrc[2];
            uint4 v3 = gsrc[3];
            *(uint4*)(Bs + nr * 72 + kc + 0)  = v0;
            *(uint4*)(Bs + nr * 72 + kc + 8)  = v1;
            *(uint4*)(Bs + nr * 72 + kc + 16) = v2;
            *(uint4*)(Bs + nr * 72 + kc + 24) = v3;
        }
        __syncthreads();

        #pragma unroll
        for (int kk = 0; kk < 64; kk += 32) {
            f16x8 a = *(const f16x8*)(As + (16 * w + c) * 72 + kk + quad * 8);
            #pragma unroll
            for (int t = 0; t < 8; t++) {
                f16x8 b = *(const f16x8*)(Bs + (16 * t + c) * 72 + kk + quad * 8);
                acc[t] = __builtin_amdgcn_mfma_f32_16x16x32_f16(a, b, acc[t], 0, 0, 0);
            }
        }
        __syncthreads();
    }

    // ---- epilogue: el/er (quad-wide reduction) + fp16 pack of h
    #pragma unroll
    for (int i = 0; i < 4; i++) {
        int gr = r0 + 16 * w + quad * 4 + i;
        float el0 = 0.f, el1 = 0.f, er0 = 0.f, er1 = 0.f;
        #pragma unroll
        for (int t = 0; t < 8; t++) {
            float hv = acc[t][i];
            float alv = al[16 * t + c];
            float arv = ar[16 * t + c];
            if (t < 4) { el0 += hv * alv; er0 += hv * arv; }
            else       { el1 += hv * alv; er1 += hv * arv; }
        }
        #pragma unroll
        for (int off = 1; off < 16; off <<= 1) {
            el0 += __shfl_xor(el0, off);
            el1 += __shfl_xor(el1, off);
            er0 += __shfl_xor(er0, off);
            er1 += __shfl_xor(er1, off);
        }
        if (c == 0 && gr < n) {
            *(float2*)(el + 2 * gr) = make_float2(el0, el1);
            *(float2*)(er + 2 * gr) = make_float2(er0, er1);
        }
        #pragma unroll
        for (int t = 0; t < 8; t++) {
            float own = acc[t][i];
            float other = __shfl_xor(own, 1);
            if ((c & 1) == 0 && gr < n) {
                __half2 hh = __floats2half2_rn(own, other);
                h16[(size_t)gr * 64 + 8 * t + (c >> 1)] = *(const uint32_t*)&hh;
            }
        }
    }
}

// ---------------------------------------------------------------------------
// Per-node weighted aggregation over CSR in-edges, fused edge-weight compute,
// + bias + ELU.  One wave per node.  Lane layout: 16 lanes x uint4 cover a
// 256 B row; wave has 4 edge slots -> 4 edges per memory/VALU instruction.
// ssrc index loads software-pipelined one iteration ahead (r5, measured win).
//   w = exp(leaky_relu(el[src].head + er[node].head))
// FUSE_FINAL=false (layer 1): write ELU'd row as fp16 (GEMM-2 input).
// FUSE_FINAL=true  (layer 2): multiply the in-register ELU'd row by
// Wl[128][16] and write out[node][16] fp32 directly — final_kernel deleted.
// After the xor-merge ALL 64 lanes hold a[0..7] for feats 8fl..8fl+7, so the
// linear costs 8 float4 loads of L1-hot Wl + 32 FMA + 4-step shfl reduce.
// ---------------------------------------------------------------------------

__device__ __forceinline__ float edge_w(float2 e, float erh, int head) {
    float x = (head ? e.y : e.x) + erh;
    x = x >= 0.f ? x : 0.2f * x;
    return __expf(x);
}

__device__ __forceinline__ void acc8(uint4 u, float w, float* a) {
    union { uint4 u4; f16x8 h8; } cv;
    cv.u4 = u;
    #pragma unroll
    for (int i = 0; i < 8; i++)
        a[i] = fmaf((float)cv.h8[i], w, a[i]);   // f16 src + f32 fma -> v_fma_mix_f32
}

template <bool FUSE_FINAL>
__global__ __launch_bounds__(256) void agg_kernel(const uint32_t* __restrict__ hb,
                                                  const int* __restrict__ ssrc,
                                                  const float* __restrict__ el,
                                                  const float* __restrict__ er,
                                                  const float* __restrict__ bias,
                                                  const int* __restrict__ offs,
                                                  const int* __restrict__ deg,
                                                  uint32_t* __restrict__ out16,
                                                  const float* __restrict__ Wl,
                                                  const float* __restrict__ bl,
                                                  float* __restrict__ outf, int n) {
    int wid = (blockIdx.x * blockDim.x + threadIdx.x) >> 6;
    int lane = threadIdx.x & 63;
    if (wid >= n) return;
    int start = offs[wid];
    int d = deg[wid];
    int g = lane >> 4;                 // edge-slot group (0..3)
    int fl = lane & 15;                // feature lane: feats 8fl..8fl+7
    int head = fl >> 3;                // feats 0..63 head0, 64..127 head1

    float2 erv = *(const float2*)(er + 2 * wid);
    float erh = head ? erv.y : erv.x;

    const int* sp = ssrc + start;
    const float2* el2 = (const float2*)el;
    const char* hbb = (const char*)hb;
    uint32_t foff = (uint32_t)(fl << 4);

    float a[8];
    #pragma unroll
    for (int i = 0; i < 8; i++) a[i] = 0.f;
    float psum = 0.f;

    int j = 0;
    if (d >= 16) {
        int s0 = sp[g];
        int s1 = sp[4 + g];
        int s2 = sp[8 + g];
        int s3 = sp[12 + g];
        for (; j + 32 <= d; j += 16) {
            // issue gathers for current indices
            float2 e0 = el2[s0];
            uint4 u0 = *(const uint4*)(hbb + (((uint32_t)s0 << 8) + foff));
            float2 e1 = el2[s1];
            uint4 u1 = *(const uint4*)(hbb + (((uint32_t)s1 << 8) + foff));
            float2 e2 = el2[s2];
            uint4 u2 = *(const uint4*)(hbb + (((uint32_t)s2 << 8) + foff));
            float2 e3 = el2[s3];
            uint4 u3 = *(const uint4*)(hbb + (((uint32_t)s3 << 8) + foff));
            // preload next iteration's indices (overlaps gather latency)
            int ns0 = sp[j + 16 + g];
            int ns1 = sp[j + 20 + g];
            int ns2 = sp[j + 24 + g];
            int ns3 = sp[j + 28 + g];
            float w0 = edge_w(e0, erh, head);
            float w1 = edge_w(e1, erh, head);
            float w2 = edge_w(e2, erh, head);
            float w3 = edge_w(e3, erh, head);
            psum += (w0 + w1) + (w2 + w3);
            acc8(u0, w0, a);
            acc8(u1, w1, a);
            acc8(u2, w2, a);
            acc8(u3, w3, a);
            s0 = ns0; s1 = ns1; s2 = ns2; s3 = ns3;
        }
        {   // final full 16-edge block (indices already in registers)
            float2 e0 = el2[s0];
            uint4 u0 = *(const uint4*)(hbb + (((uint32_t)s0 << 8) + foff));
            float2 e1 = el2[s1];
            uint4 u1 = *(const uint4*)(hbb + (((uint32_t)s1 << 8) + foff));
            float2 e2 = el2[s2];
            uint4 u2 = *(const uint4*)(hbb + (((uint32_t)s2 << 8) + foff));
            float2 e3 = el2[s3];
            uint4 u3 = *(const uint4*)(hbb + (((uint32_t)s3 << 8) + foff));
            float w0 = edge_w(e0, erh, head);
            float w1 = edge_w(e1, erh, head);
            float w2 = edge_w(e2, erh, head);
            float w3 = edge_w(e3, erh, head);
            psum += (w0 + w1) + (w2 + w3);
            acc8(u0, w0, a);
            acc8(u1, w1, a);
            acc8(u2, w2, a);
            acc8(u3, w3, a);
            j += 16;
        }
    }
    if (j < d) {                       // masked tail, up to 15 edges
        int last = d - 1;
        int i0 = j + g, i1 = j + 4 + g, i2 = j + 8 + g, i3 = j + 12 + g;
        int s0 = sp[min(i0, last)];
        int s1 = sp[min(i1, last)];
        int s2 = sp[min(i2, last)];
        int s3 = sp[min(i3, last)];
        float2 e0 = el2[s0];
        uint4 u0 = *(const uint4*)(hbb + (((uint32_t)s0 << 8) + foff));
        float2 e1 = el2[s1];
        uint4 u1 = *(const uint4*)(hbb + (((uint32_t)s1 << 8) + foff));
        float2 e2 = el2[s2];
        uint4 u2 = *(const uint4*)(hbb + (((uint32_t)s2 << 8) + foff));
        float2 e3 = el2[s3];
        uint4 u3 = *(const uint4*)(hbb + (((uint32_t)s3 << 8) + foff));
        float w0 = (i0 <= last) ? edge_w(e0, erh, head) : 0.f;
        float w1 = (i1 <= last) ? edge_w(e1, erh, head) : 0.f;
        float w2 = (i2 <= last) ? edge_w(e2, erh, head) : 0.f;
        float w3 = (i3 <= last) ? edge_w(e3, erh, head) : 0.f;
        psum += (w0 + w1) + (w2 + w3);
        acc8(u0, w0, a);
        acc8(u1, w1, a);
        acc8(u2, w2, a);
        acc8(u3, w3, a);
    }

    // merge the four per-slot edge streams (xor 16/32 keeps fl fixed);
    // afterwards ALL lanes hold the merged a[] and psum.
    #pragma unroll
    for (int i = 0; i < 8; i++) {
        a[i] += __shfl_xor(a[i], 16);
        a[i] += __shfl_xor(a[i], 32);
    }
    psum += __shfl_xor(psum, 16);
    psum += __shfl_xor(psum, 32);

    float inv = 1.f / (psum + 1e-9f);
    float4 b0 = *(const float4*)(bias + 8 * fl);
    float4 b1 = *(const float4*)(bias + 8 * fl + 4);
    float o[8];
    o[0] = fmaf(a[0], inv, b0.x);
    o[1] = fmaf(a[1], inv, b0.y);
    o[2] = fmaf(a[2], inv, b0.z);
    o[3] = fmaf(a[3], inv, b0.w);
    o[4] = fmaf(a[4], inv, b1.x);
    o[5] = fmaf(a[5], inv, b1.y);
    o[6] = fmaf(a[6], inv, b1.z);
    o[7] = fmaf(a[7], inv, b1.w);
    #pragma unroll
    for (int i = 0; i < 8; i++)
        o[i] = o[i] > 0.f ? o[i] : (__expf(o[i]) - 1.f);   // ELU fused

    if constexpr (!FUSE_FINAL) {
        if (lane < 16) {
            __half2 h01 = __floats2half2_rn(o[0], o[1]);
            __half2 h23 = __floats2half2_rn(o[2], o[3]);
            __half2 h45 = __floats2half2_rn(o[4], o[5]);
            __half2 h67 = __floats2half2_rn(o[6], o[7]);
            uint4 ov = make_uint4(*(const uint32_t*)&h01, *(const uint32_t*)&h23,
                                  *(const uint32_t*)&h45, *(const uint32_t*)&h67);
            ((uint4*)(out16 + (size_t)wid * 64))[lane] = ov;
        }
    } else {
        // fused final linear: lane (g, fl) accumulates cols 4g..4g+3 over its
        // 8 feats; Wl is 8 KB, L1-resident (read by every wave).
        const float4* Wl4 = (const float4*)Wl;   // row f -> 4 float4 (16 cols)
        float p0 = 0.f, p1 = 0.f, p2 = 0.f, p3 = 0.f;
        #pragma unroll
        for (int i = 0; i < 8; i++) {
            float4 wv = Wl4[(8 * fl + i) * 4 + g];
            p0 = fmaf(o[i], wv.x, p0);
            p1 = fmaf(o[i], wv.y, p1);
            p2 = fmaf(o[i], wv.z, p2);
            p3 = fmaf(o[i], wv.w, p3);
        }
        #pragma unroll
        for (int off = 1; off < 16; off <<= 1) {
            p0 += __shfl_xor(p0, off);
            p1 += __shfl_xor(p1, off);
            p2 += __shfl_xor(p2, off);
            p3 += __shfl_xor(p3, off);
        }
        if (fl == 0) {
            float4 blv = ((const float4*)bl)[g];
            float4 ov = make_float4(p0 + blv.x, p1 + blv.y, p2 + blv.z, p3 + blv.w);
            *(float4*)(outf + (size_t)wid * OUT_SZ + 4 * g) = ov;
        }
    }
}

// ---------------------------------------------------------------------------

extern "C" void kernel_launch(void* const* d_in, const int* in_sizes, int n_in,
                              void* d_out, int out_size, void* d_ws, size_t ws_size,
                              hipStream_t stream) {
    const float* features = (const float*)d_in[0];
    const int*   src      = (const int*)d_in[1];
    const int*   dst      = (const int*)d_in[2];
    const float* W1  = (const float*)d_in[3];
    const float* al1 = (const float*)d_in[4];
    const float* ar1 = (const float*)d_in[5];
    const float* b1  = (const float*)d_in[6];
    const float* W2  = (const float*)d_in[7];
    const float* al2 = (const float*)d_in[8];
    const float* ar2 = (const float*)d_in[9];
    const float* b2  = (const float*)d_in[10];
    const float* Wl  = (const float*)d_in[11];
    const float* bl  = (const float*)d_in[12];
    float* out = (float*)d_out;

    const int n = N_NODES, e = N_EDGES;

    // workspace carve-up (all chunks 256B-aligned)
    char* w = (char*)d_ws;
    uint32_t* h16 = (uint32_t*)w;       w += (size_t)n * 64 * 4;       // 25.6 MB
    uint32_t* x1  = (uint32_t*)w;       w += (size_t)n * 64 * 4;       // 25.6 MB
    char* bbuf    = w;                  w += 26 * 1024 * 1024;         // 26 MB bucketbuf
    float* el   = (float*)w;            w += (size_t)n * 2 * 4;        // 0.8 MB
    float* er   = (float*)w;            w += (size_t)n * 2 * 4;        // 0.8 MB
    int* deg    = (int*)w;              w += 400128;
    int* offs   = (int*)w;              w += 400128;
    int* ssrc   = (int*)w;              w += (size_t)e * 4;            // 6.4 MB
    int* counts = (int*)w;              w += 1024;
    int* bases  = (int*)w;              w += 1024;
    _Float16* Wt1 = (_Float16*)w;       w += 128 * IN_SIZE * 2;        // 64 KB
    _Float16* Wt2 = (_Float16*)w;       w += 128 * DMODEL * 2;         // 32 KB
    int2* bucketbuf = (int2*)bbuf;      // 196*16384*8 = 25.69 MB

    const int binBlocks = (e + EPB - 1) / EPB;   // 391
    const int gemmBlocks = (n + 63) / 64;        // 1563
    const int aggBlocks = (n + 3) / 4;           // 25000
    (void)out_size;

    // ---- CSR build (once; graph shared by both layers)
    hipMemsetAsync(counts, 0, NB * 4, stream);
    bin_kernel<<<binBlocks, 256, 0, stream>>>(src, dst, counts, bucketbuf, e);
    bucket_scan_kernel<<<1, 256, 0, stream>>>(counts, bases);
    csr_kernel<<<NB, 256, 0, stream>>>(bucketbuf, counts, bases, deg, offs, ssrc, n);

    // ---- weight prep (fp16 transpose; tiny)
    wt_kernel<IN_SIZE><<<(128 * IN_SIZE + 255) / 256, 256, 0, stream>>>(W1, Wt1);
    wt_kernel<DMODEL><<<(128 * DMODEL + 255) / 256, 256, 0, stream>>>(W2, Wt2);

    // ---- layer 1
    gemm_attn_kernel<IN_SIZE, false><<<gemmBlocks, 256, 0, stream>>>(features, Wt1, al1, ar1,
                                                                     h16, el, er, n);
    agg_kernel<false><<<aggBlocks, 256, 0, stream>>>(h16, ssrc, el, er, b1, offs, deg,
                                                     x1, nullptr, nullptr, nullptr, n);

    // ---- layer 2 (x1 holds ELU'd layer-1 output, fp16); final linear fused
    gemm_attn_kernel<DMODEL, true><<<gemmBlocks, 256, 0, stream>>>(x1, Wt2, al2, ar2,
                                                                   h16, el, er, n);
    agg_kernel<true><<<aggBlocks, 256, 0, stream>>>(h16, ssrc, el, er, b2, offs, deg,
                                                    nullptr, Wl, bl, out, n);

    (void)in_sizes; (void)n_in; (void)ws_size;
}

// Round 7
// 421.513 us; speedup vs baseline: 1.1578x; 1.1578x over previous
//
#include <hip/hip_runtime.h>
#include <hip/hip_fp16.h>

#define N_NODES 100000
#define N_EDGES 1600000
#define IN_SIZE 256
#define HID 64
#define HEADS 2
#define DMODEL 128   // HEADS*HID
#define OUT_SZ 16

// CSR build via bucketed counting sort (r2 geometry — measured best)
#define BSHIFT 9                       // 512 nodes per bucket
#define BNODES 512
#define NB 196                         // ceil(100000/512)
#define CAP 16384                      // bucket capacity (mean 8163, +90 sigma)
#define EPB 4096                       // edges per bin_kernel block

typedef _Float16 f16x4 __attribute__((ext_vector_type(4)));
typedef _Float16 f16x8 __attribute__((ext_vector_type(8)));
typedef float f32x4 __attribute__((ext_vector_type(4)));

// ---------------------------------------------------------------------------
// Fused weight prep + counts zeroing.  Launches FIRST (stream-ordered before
// bin_kernel), so the counts memset dispatch is deleted.
// Blocks [0,128): Wt1 = transpose(W1) fp16; blocks [128,192): Wt2.
// ---------------------------------------------------------------------------

__global__ __launch_bounds__(256) void wt_fused_kernel(const float* __restrict__ W1,
                                                       _Float16* __restrict__ Wt1,
                                                       const float* __restrict__ W2,
                                                       _Float16* __restrict__ Wt2,
                                                       int* __restrict__ counts) {
    int tid = threadIdx.x;
    if (blockIdx.x == 0 && tid < NB) counts[tid] = 0;
    int i = blockIdx.x * 256 + tid;
    if (i < 128 * IN_SIZE) {
        int nr = i / IN_SIZE;
        int k = i - nr * IN_SIZE;
        Wt1[i] = (_Float16)W1[(size_t)k * 128 + nr];
    } else {
        int j = i - 128 * IN_SIZE;
        if (j < 128 * DMODEL) {
            int nr = j / DMODEL;
            int k = j - nr * DMODEL;
            Wt2[j] = (_Float16)W2[(size_t)k * 128 + nr];
        }
    }
}

// ---------------------------------------------------------------------------
// Phase 1: bin edges by dst>>9 into per-bucket regions.
// ---------------------------------------------------------------------------

__global__ __launch_bounds__(256) void bin_kernel(const int* __restrict__ src,
                                                  const int* __restrict__ dst,
                                                  int* __restrict__ counts,
                                                  int2* __restrict__ bucketbuf, int e) {
    __shared__ int hist[NB];
    __shared__ int base[NB];
    int tid = threadIdx.x;
    int start = blockIdx.x * EPB;
    for (int i = tid; i < NB; i += 256) hist[i] = 0;
    __syncthreads();
    int pack[16];
    #pragma unroll
    for (int i = 0; i < 16; i++) {
        int idx = start + i * 256 + tid;
        int p = -1;
        if (idx < e) {
            int b = dst[idx] >> BSHIFT;
            int r = atomicAdd(&hist[b], 1);     // LDS atomic: local rank
            p = (b << 16) | r;
        }
        pack[i] = p;
    }
    __syncthreads();
    for (int i = tid; i < NB; i += 256)
        base[i] = atomicAdd(&counts[i], hist[i]);   // reserve chunk per bucket
    __syncthreads();
    #pragma unroll
    for (int i = 0; i < 16; i++) {
        int idx = start + i * 256 + tid;
        int p = pack[i];
        if (p >= 0) {
            int b = p >> 16;
            int pos = base[b] + (p & 0xffff);
            if (pos < CAP)
                bucketbuf[(size_t)b * CAP + pos] = make_int2(src[idx], dst[idx]);
        }
    }
}

// ---------------------------------------------------------------------------
// Phase 2: per-bucket CSR (all-LDS histogram/scan/scatter; L2-local writes).
// The global bucket-base scan is computed INLINE per block (196 entries,
// redundant across blocks, ~2 us in parallel) — the serial 1-block
// bucket_scan dispatch is deleted.
// Writes src-only edge list in CSR order (ssrc) — dst is implicit (= node).
// ---------------------------------------------------------------------------

__global__ __launch_bounds__(256) void csr_kernel(const int2* __restrict__ bucketbuf,
                                                  const int* __restrict__ counts,
                                                  int* __restrict__ deg,
                                                  int* __restrict__ offs,
                                                  int* __restrict__ ssrc, int n) {
    __shared__ int hist[BNODES];
    __shared__ int cursor[BNODES];
    __shared__ int lds[256];
    int b = blockIdx.x;
    int tid = threadIdx.x;

    // inline scan of counts[0..NB) -> this block's base
    int t = (tid < NB) ? min(counts[tid], CAP) : 0;
    lds[tid] = t;
    __syncthreads();
    for (int off = 1; off < 256; off <<= 1) {
        int x = 0;
        if (tid >= off) x = lds[tid - off];
        __syncthreads();
        lds[tid] += x;
        __syncthreads();
    }
    int base = (b == 0) ? 0 : lds[b - 1];   // exclusive prefix for this bucket
    int cnt = min(counts[b], CAP);
    __syncthreads();

    int node0 = b << BSHIFT;
    const int2* ebuf = bucketbuf + (size_t)b * CAP;

    hist[tid] = 0;
    hist[tid + 256] = 0;
    __syncthreads();
    for (int i = tid; i < cnt; i += 256)
        atomicAdd(&hist[ebuf[i].y - node0], 1);
    __syncthreads();

    int h0 = hist[2 * tid], h1 = hist[2 * tid + 1];
    lds[tid] = h0 + h1;
    __syncthreads();
    for (int off = 1; off < 256; off <<= 1) {
        int x = 0;
        if (tid >= off) x = lds[tid - off];
        __syncthreads();
        lds[tid] += x;
        __syncthreads();
    }
    int excl = lds[tid] - (h0 + h1);
    cursor[2 * tid] = excl;
    cursor[2 * tid + 1] = excl + h0;
    int g0 = node0 + 2 * tid, g1 = g0 + 1;
    if (g0 < n) { deg[g0] = h0; offs[g0] = base + excl; }
    if (g1 < n) { deg[g1] = h1; offs[g1] = base + excl + h0; }
    __syncthreads();

    for (int i = tid; i < cnt; i += 256) {
        int2 ed = ebuf[i];
        int p = atomicAdd(&cursor[ed.y - node0], 1);   // LDS atomic
        ssrc[base + p] = ed.x;                         // src in CSR order
    }
}

// ---------------------------------------------------------------------------
// Fused MFMA GEMM + attention coefficients + fp16 pack.
//   h = A[n][K] @ W[K][128]  (fp16 inputs, fp32 accum)
//   el[n][h], er[n][h] computed in-register from the accumulators
//   h16[n][128] = fp16(h)   (compact; the ONLY materialization of h)
// F16IN=false: A is fp32 [n][K]; F16IN=true: A is packed fp16 (uint32 pairs,
// h16 layout, K/2 u32 per row; u32 j <-> cols (2j, 2j+1)).
// ---------------------------------------------------------------------------

template <int K, bool F16IN>
__global__ __launch_bounds__(256) void gemm_attn_kernel(const void* __restrict__ Ap,
                                                        const _Float16* __restrict__ Wt,
                                                        const float* __restrict__ al,
                                                        const float* __restrict__ ar,
                                                        uint32_t* __restrict__ h16,
                                                        float* __restrict__ el,
                                                        float* __restrict__ er, int n) {
    __shared__ _Float16 As[64 * 72];
    __shared__ _Float16 Bs[128 * 72];
    int tid = threadIdx.x;
    int w = tid >> 6;
    int lane = tid & 63;
    int c = lane & 15;
    int quad = lane >> 4;
    int r0 = blockIdx.x * 64;

    f32x4 acc[8];
    #pragma unroll
    for (int t = 0; t < 8; t++) acc[t] = (f32x4){0.f, 0.f, 0.f, 0.f};

    for (int kt = 0; kt < K; kt += 64) {
        // stage A tile (64 rows x 64 k)
        {
            int lr = tid >> 4;           // 0..15
            int lc = (tid & 15) * 4;     // 0..60 (halves)
            #pragma unroll
            for (int q = 0; q < 4; q++) {
                int row = lr + 16 * q;
                int gr = r0 + row;
                if constexpr (F16IN) {
                    const uint32_t* Af = (const uint32_t*)Ap;
                    uint2 v = make_uint2(0u, 0u);
                    if (gr < n) v = *(const uint2*)(Af + (size_t)gr * (K / 2) + (kt + lc) / 2);
                    *(uint2*)(As + row * 72 + lc) = v;
                } else {
                    const float* Af = (const float*)Ap;
                    float4 v = make_float4(0.f, 0.f, 0.f, 0.f);
                    if (gr < n) v = *(const float4*)(Af + (size_t)gr * K + kt + lc);
                    f16x4 hv = {(_Float16)v.x, (_Float16)v.y, (_Float16)v.z, (_Float16)v.w};
                    *(f16x4*)(As + row * 72 + lc) = hv;
                }
            }
            // stage Wt tile (128 n-rows x 64 k), fp16; 32 halves per thread
            int nr = tid >> 1;           // 0..127
            int kc = (tid & 1) * 32;     // 0 or 32
            const uint4* gsrc = (const uint4*)(Wt + (size_t)nr * K + kt + kc);
            uint4 v0 = gsrc[0];
            uint4 v1 = gsrc[1];
            uint4 v2 = gsrc[2];
            uint4 v3 = gsrc[3];
            *(uint4*)(Bs + nr * 72 + kc + 0)  = v0;
            *(uint4*)(Bs + nr * 72 + kc + 8)  = v1;
            *(uint4*)(Bs + nr * 72 + kc + 16) = v2;
            *(uint4*)(Bs + nr * 72 + kc + 24) = v3;
        }
        __syncthreads();

        #pragma unroll
        for (int kk = 0; kk < 64; kk += 32) {
            f16x8 a = *(const f16x8*)(As + (16 * w + c) * 72 + kk + quad * 8);
            #pragma unroll
            for (int t = 0; t < 8; t++) {
                f16x8 b = *(const f16x8*)(Bs + (16 * t + c) * 72 + kk + quad * 8);
                acc[t] = __builtin_amdgcn_mfma_f32_16x16x32_f16(a, b, acc[t], 0, 0, 0);
            }
        }
        __syncthreads();
    }

    // ---- epilogue: el/er (quad-wide reduction) + fp16 pack of h
    #pragma unroll
    for (int i = 0; i < 4; i++) {
        int gr = r0 + 16 * w + quad * 4 + i;
        float el0 = 0.f, el1 = 0.f, er0 = 0.f, er1 = 0.f;
        #pragma unroll
        for (int t = 0; t < 8; t++) {
            float hv = acc[t][i];
            float alv = al[16 * t + c];
            float arv = ar[16 * t + c];
            if (t < 4) { el0 += hv * alv; er0 += hv * arv; }
            else       { el1 += hv * alv; er1 += hv * arv; }
        }
        #pragma unroll
        for (int off = 1; off < 16; off <<= 1) {
            el0 += __shfl_xor(el0, off);
            el1 += __shfl_xor(el1, off);
            er0 += __shfl_xor(er0, off);
            er1 += __shfl_xor(er1, off);
        }
        if (c == 0 && gr < n) {
            *(float2*)(el + 2 * gr) = make_float2(el0, el1);
            *(float2*)(er + 2 * gr) = make_float2(er0, er1);
        }
        #pragma unroll
        for (int t = 0; t < 8; t++) {
            float own = acc[t][i];
            float other = __shfl_xor(own, 1);
            if ((c & 1) == 0 && gr < n) {
                __half2 hh = __floats2half2_rn(own, other);
                h16[(size_t)gr * 64 + 8 * t + (c >> 1)] = *(const uint32_t*)&hh;
            }
        }
    }
}

// ---------------------------------------------------------------------------
// Per-node weighted aggregation over CSR in-edges, fused edge-weight compute,
// + bias + ELU, fp16 output.  One wave per node.  (Exact r5 structure —
// best measured: 69.4 us.)  Lane layout: 16 lanes x uint4 cover a 256 B row;
// wave has 4 edge slots -> 4 edges per memory/VALU instruction.
//   w = exp(leaky_relu(el[src].head + er[node].head))
// ssrc index loads software-pipelined one iteration ahead.
// Cross-slot merge via __shfl_xor(16/32).  Normalization in epilogue.
// ---------------------------------------------------------------------------

__device__ __forceinline__ float edge_w(float2 e, float erh, int head) {
    float x = (head ? e.y : e.x) + erh;
    x = x >= 0.f ? x : 0.2f * x;
    return __expf(x);
}

__device__ __forceinline__ void acc8(uint4 u, float w, float* a) {
    union { uint4 u4; f16x8 h8; } cv;
    cv.u4 = u;
    #pragma unroll
    for (int i = 0; i < 8; i++)
        a[i] = fmaf((float)cv.h8[i], w, a[i]);   // f16 src + f32 fma -> v_fma_mix_f32
}

__global__ __launch_bounds__(256) void agg_kernel(const uint32_t* __restrict__ hb,
                                                  const int* __restrict__ ssrc,
                                                  const float* __restrict__ el,
                                                  const float* __restrict__ er,
                                                  const float* __restrict__ bias,
                                                  const int* __restrict__ offs,
                                                  const int* __restrict__ deg,
                                                  uint32_t* __restrict__ out16, int n) {
    int wid = (blockIdx.x * blockDim.x + threadIdx.x) >> 6;
    int lane = threadIdx.x & 63;
    if (wid >= n) return;
    int start = offs[wid];
    int d = deg[wid];
    int g = lane >> 4;                 // edge-slot group (0..3)
    int fl = lane & 15;                // feature lane: feats 8fl..8fl+7
    int head = fl >> 3;                // feats 0..63 head0, 64..127 head1

    float2 erv = *(const float2*)(er + 2 * wid);
    float erh = head ? erv.y : erv.x;

    const int* sp = ssrc + start;
    const float2* el2 = (const float2*)el;
    const char* hbb = (const char*)hb;
    uint32_t foff = (uint32_t)(fl << 4);

    float a[8];
    #pragma unroll
    for (int i = 0; i < 8; i++) a[i] = 0.f;
    float psum = 0.f;

    int j = 0;
    if (d >= 16) {
        int s0 = sp[g];
        int s1 = sp[4 + g];
        int s2 = sp[8 + g];
        int s3 = sp[12 + g];
        for (; j + 32 <= d; j += 16) {
            // issue gathers for current indices
            float2 e0 = el2[s0];
            uint4 u0 = *(const uint4*)(hbb + (((uint32_t)s0 << 8) + foff));
            float2 e1 = el2[s1];
            uint4 u1 = *(const uint4*)(hbb + (((uint32_t)s1 << 8) + foff));
            float2 e2 = el2[s2];
            uint4 u2 = *(const uint4*)(hbb + (((uint32_t)s2 << 8) + foff));
            float2 e3 = el2[s3];
            uint4 u3 = *(const uint4*)(hbb + (((uint32_t)s3 << 8) + foff));
            // preload next iteration's indices (overlaps gather latency)
            int ns0 = sp[j + 16 + g];
            int ns1 = sp[j + 20 + g];
            int ns2 = sp[j + 24 + g];
            int ns3 = sp[j + 28 + g];
            float w0 = edge_w(e0, erh, head);
            float w1 = edge_w(e1, erh, head);
            float w2 = edge_w(e2, erh, head);
            float w3 = edge_w(e3, erh, head);
            psum += (w0 + w1) + (w2 + w3);
            acc8(u0, w0, a);
            acc8(u1, w1, a);
            acc8(u2, w2, a);
            acc8(u3, w3, a);
            s0 = ns0; s1 = ns1; s2 = ns2; s3 = ns3;
        }
        {   // final full 16-edge block (indices already in registers)
            float2 e0 = el2[s0];
            uint4 u0 = *(const uint4*)(hbb + (((uint32_t)s0 << 8) + foff));
            float2 e1 = el2[s1];
            uint4 u1 = *(const uint4*)(hbb + (((uint32_t)s1 << 8) + foff));
            float2 e2 = el2[s2];
            uint4 u2 = *(const uint4*)(hbb + (((uint32_t)s2 << 8) + foff));
            float2 e3 = el2[s3];
            uint4 u3 = *(const uint4*)(hbb + (((uint32_t)s3 << 8) + foff));
            float w0 = edge_w(e0, erh, head);
            float w1 = edge_w(e1, erh, head);
            float w2 = edge_w(e2, erh, head);
            float w3 = edge_w(e3, erh, head);
            psum += (w0 + w1) + (w2 + w3);
            acc8(u0, w0, a);
            acc8(u1, w1, a);
            acc8(u2, w2, a);
            acc8(u3, w3, a);
            j += 16;
        }
    }
    if (j < d) {                       // masked tail, up to 15 edges
        int last = d - 1;
        int i0 = j + g, i1 = j + 4 + g, i2 = j + 8 + g, i3 = j + 12 + g;
        int s0 = sp[min(i0, last)];
        int s1 = sp[min(i1, last)];
        int s2 = sp[min(i2, last)];
        int s3 = sp[min(i3, last)];
        float2 e0 = el2[s0];
        uint4 u0 = *(const uint4*)(hbb + (((uint32_t)s0 << 8) + foff));
        float2 e1 = el2[s1];
        uint4 u1 = *(const uint4*)(hbb + (((uint32_t)s1 << 8) + foff));
        float2 e2 = el2[s2];
        uint4 u2 = *(const uint4*)(hbb + (((uint32_t)s2 << 8) + foff));
        float2 e3 = el2[s3];
        uint4 u3 = *(const uint4*)(hbb + (((uint32_t)s3 << 8) + foff));
        float w0 = (i0 <= last) ? edge_w(e0, erh, head) : 0.f;
        float w1 = (i1 <= last) ? edge_w(e1, erh, head) : 0.f;
        float w2 = (i2 <= last) ? edge_w(e2, erh, head) : 0.f;
        float w3 = (i3 <= last) ? edge_w(e3, erh, head) : 0.f;
        psum += (w0 + w1) + (w2 + w3);
        acc8(u0, w0, a);
        acc8(u1, w1, a);
        acc8(u2, w2, a);
        acc8(u3, w3, a);
    }

    // merge the four per-slot edge streams (xor 16/32 keeps fl fixed)
    #pragma unroll
    for (int i = 0; i < 8; i++) {
        a[i] += __shfl_xor(a[i], 16);
        a[i] += __shfl_xor(a[i], 32);
    }
    psum += __shfl_xor(psum, 16);
    psum += __shfl_xor(psum, 32);

    if (lane < 16) {
        float inv = 1.f / (psum + 1e-9f);
        float4 b0 = *(const float4*)(bias + 8 * lane);
        float4 b1 = *(const float4*)(bias + 8 * lane + 4);
        float o[8];
        o[0] = fmaf(a[0], inv, b0.x);
        o[1] = fmaf(a[1], inv, b0.y);
        o[2] = fmaf(a[2], inv, b0.z);
        o[3] = fmaf(a[3], inv, b0.w);
        o[4] = fmaf(a[4], inv, b1.x);
        o[5] = fmaf(a[5], inv, b1.y);
        o[6] = fmaf(a[6], inv, b1.z);
        o[7] = fmaf(a[7], inv, b1.w);
        #pragma unroll
        for (int i = 0; i < 8; i++)
            o[i] = o[i] > 0.f ? o[i] : (__expf(o[i]) - 1.f);   // ELU fused
        __half2 h01 = __floats2half2_rn(o[0], o[1]);
        __half2 h23 = __floats2half2_rn(o[2], o[3]);
        __half2 h45 = __floats2half2_rn(o[4], o[5]);
        __half2 h67 = __floats2half2_rn(o[6], o[7]);
        uint4 ov = make_uint4(*(const uint32_t*)&h01, *(const uint32_t*)&h23,
                              *(const uint32_t*)&h45, *(const uint32_t*)&h67);
        ((uint4*)(out16 + (size_t)wid * 64))[lane] = ov;
    }
}

// ---------------------------------------------------------------------------
// Final linear: out[n][16] = x[n][128](fp16) @ Wl[128][16] + bl.
// Block = 16 nodes x 16 cols; Wl staged in LDS.  (Restored — fusing this
// into agg's epilogue serialized 8 scattered vmcnt-exposed Wl loads per wave
// and cost +83 us; see r6 post-mortem.)
// ---------------------------------------------------------------------------

__global__ __launch_bounds__(256) void final_kernel(const uint32_t* __restrict__ x16,
                                                    const float* __restrict__ Wl,
                                                    const float* __restrict__ bl,
                                                    float* __restrict__ out, int n) {
    __shared__ float Ws[DMODEL * OUT_SZ];
    __shared__ float bs[OUT_SZ];
    int tid = threadIdx.x;
    for (int i = tid; i < DMODEL * OUT_SZ / 4; i += 256)
        ((float4*)Ws)[i] = ((const float4*)Wl)[i];
    if (tid < OUT_SZ) bs[tid] = bl[tid];
    __syncthreads();
    int node = blockIdx.x * 16 + (tid >> 4);
    int c = tid & 15;
    if (node >= n) return;
    const uint2* xr = (const uint2*)(x16 + (size_t)node * 64);
    float acc = bs[c];
    #pragma unroll
    for (int kk = 0; kk < 32; kk++) {
        uint2 v = xr[kk];
        float2 f0 = __half22float2(*(const __half2*)&v.x);
        float2 f1 = __half22float2(*(const __half2*)&v.y);
        acc += f0.x * Ws[(4 * kk + 0) * OUT_SZ + c];
        acc += f0.y * Ws[(4 * kk + 1) * OUT_SZ + c];
        acc += f1.x * Ws[(4 * kk + 2) * OUT_SZ + c];
        acc += f1.y * Ws[(4 * kk + 3) * OUT_SZ + c];
    }
    out[(size_t)node * OUT_SZ + c] = acc;
}

// ---------------------------------------------------------------------------

extern "C" void kernel_launch(void* const* d_in, const int* in_sizes, int n_in,
                              void* d_out, int out_size, void* d_ws, size_t ws_size,
                              hipStream_t stream) {
    const float* features = (const float*)d_in[0];
    const int*   src      = (const int*)d_in[1];
    const int*   dst      = (const int*)d_in[2];
    const float* W1  = (const float*)d_in[3];
    const float* al1 = (const float*)d_in[4];
    const float* ar1 = (const float*)d_in[5];
    const float* b1  = (const float*)d_in[6];
    const float* W2  = (const float*)d_in[7];
    const float* al2 = (const float*)d_in[8];
    const float* ar2 = (const float*)d_in[9];
    const float* b2  = (const float*)d_in[10];
    const float* Wl  = (const float*)d_in[11];
    const float* bl  = (const float*)d_in[12];
    float* out = (float*)d_out;

    const int n = N_NODES, e = N_EDGES;

    // workspace carve-up (all chunks 256B-aligned)
    char* w = (char*)d_ws;
    uint32_t* h16 = (uint32_t*)w;       w += (size_t)n * 64 * 4;       // 25.6 MB
    uint32_t* x1  = (uint32_t*)w;       w += (size_t)n * 64 * 4;       // 25.6 MB
    uint32_t* x2  = (uint32_t*)w;       w += 26 * 1024 * 1024;         // 26 MB (aliases bucketbuf)
    float* el   = (float*)w;            w += (size_t)n * 2 * 4;        // 0.8 MB
    float* er   = (float*)w;            w += (size_t)n * 2 * 4;        // 0.8 MB
    int* deg    = (int*)w;              w += 400128;
    int* offs   = (int*)w;              w += 400128;
    int* ssrc   = (int*)w;              w += (size_t)e * 4;            // 6.4 MB
    int* counts = (int*)w;              w += 1024;
    _Float16* Wt1 = (_Float16*)w;       w += 128 * IN_SIZE * 2;        // 64 KB
    _Float16* Wt2 = (_Float16*)w;       w += 128 * DMODEL * 2;         // 32 KB
    // bucketbuf (25.7 MB) aliases x2: consumed by csr_kernel before agg2
    // writes x2 (stream-ordered).
    int2* bucketbuf = (int2*)x2;

    const int binBlocks = (e + EPB - 1) / EPB;   // 391
    const int wtBlocks = (128 * IN_SIZE + 128 * DMODEL + 255) / 256;   // 192
    const int gemmBlocks = (n + 63) / 64;        // 1563
    const int aggBlocks = (n + 3) / 4;           // 25000
    const int finalBlocks = (n + 15) / 16;       // 6250

    // ---- weight prep + counts zeroing (independent; runs before bin)
    wt_fused_kernel<<<wtBlocks, 256, 0, stream>>>(W1, Wt1, W2, Wt2, counts);

    // ---- CSR build (once; graph shared by both layers); scan fused in csr
    bin_kernel<<<binBlocks, 256, 0, stream>>>(src, dst, counts, bucketbuf, e);
    csr_kernel<<<NB, 256, 0, stream>>>(bucketbuf, counts, deg, offs, ssrc, n);

    // ---- layer 1
    gemm_attn_kernel<IN_SIZE, false><<<gemmBlocks, 256, 0, stream>>>(features, Wt1, al1, ar1,
                                                                     h16, el, er, n);
    agg_kernel<<<aggBlocks, 256, 0, stream>>>(h16, ssrc, el, er, b1, offs, deg, x1, n);

    // ---- layer 2 (x1 holds ELU'd layer-1 output, fp16)
    gemm_attn_kernel<DMODEL, true><<<gemmBlocks, 256, 0, stream>>>(x1, Wt2, al2, ar2,
                                                                   h16, el, er, n);
    agg_kernel<<<aggBlocks, 256, 0, stream>>>(h16, ssrc, el, er, b2, offs, deg, x2, n);

    // ---- final linear
    final_kernel<<<finalBlocks, 256, 0, stream>>>(x2, Wl, bl, out, n);

    (void)in_sizes; (void)n_in; (void)out_size; (void)ws_size;
}